// Round 1
// baseline (1595.448 us; speedup 1.0000x reference)
//
#include <hip/hip_runtime.h>
#include <math.h>

// NormVoxels: trilinear gather + sigmoid-weighted scatter-add update.
// d_in: [0]=t(int32,N) [1]=pos(f32,N*3) [2]=lr(f32,1) [3]=sigma(f32,N)
//       [4]=target_norm(f32,N*3) [5]=voxel_array(f32,8*128^3*3)
// d_out: value(f32,N*3) ++ new_voxel(f32,8*128^3*3)

#define GRES 128
constexpr float RMIN_F = -1.5f;
constexpr float STEP_F = 3.0f / 128.0f;  // 0.0234375, exact in fp32

__global__ __launch_bounds__(256) void normvoxels_update(
    const int*   __restrict__ t,
    const float* __restrict__ pos,
    const float* __restrict__ lr_p,
    const float* __restrict__ sigma,
    const float* __restrict__ target,
    const float* __restrict__ voxel_in,
    float*       __restrict__ out_value,
    float*       __restrict__ out_voxel,
    int N)
{
    int i = blockIdx.x * blockDim.x + threadIdx.x;
    if (i >= N) return;

    const float lr = lr_p[0];

    const float px = pos[3 * i + 0] - RMIN_F;
    const float py = pos[3 * i + 1] - RMIN_F;
    const float pz = pos[3 * i + 2] - RMIN_F;

    const int mx = (int)floorf(px / STEP_F);
    const int my = (int)floorf(py / STEP_F);
    const int mz = (int)floorf(pz / STEP_F);

    // frac = mod(pos_s, STEP)/STEP  (jnp.mod == fmod for positive operands)
    const float u = fmodf(px, STEP_F) / STEP_F;
    const float v = fmodf(py, STEP_F) / STEP_F;
    const float w = fmodf(pz, STEP_F) / STEP_F;

    const int x0 = min(max(mx,     0), GRES - 1);
    const int x1 = min(max(mx + 1, 0), GRES - 1);
    const int y0 = min(max(my,     0), GRES - 1);
    const int y1 = min(max(my + 1, 0), GRES - 1);
    const int z0 = min(max(mz,     0), GRES - 1);
    const int z1 = min(max(mz + 1, 0), GRES - 1);

    float c[8];
    c[0] = (1.f - u) * (1.f - v) * (1.f - w);
    c[1] =        u  * (1.f - v) * (1.f - w);
    c[2] = (1.f - u) *        v  * (1.f - w);
    c[3] =        u  *        v  * (1.f - w);
    c[4] = (1.f - u) * (1.f - v) *        w;
    c[5] =        u  * (1.f - v) *        w;
    c[6] = (1.f - u) *        v  *        w;
    c[7] =        u  *        v  *        w;

    const float sw = 1.0f - expf(-sigma[i]);
    const float lrsw = lr * sw;

    const float tx = target[3 * i + 0];
    const float ty = target[3 * i + 1];
    const float tz = target[3 * i + 2];

    const size_t tbase = (size_t)t[i] * GRES * GRES * GRES * 3;

    float vx = 0.f, vy = 0.f, vz = 0.f;

    #pragma unroll
    for (int k = 0; k < 8; ++k) {
        const int xi = (k & 1) ? x1 : x0;
        const int yi = (k & 2) ? y1 : y0;
        const int zi = (k & 4) ? z1 : z0;
        const size_t base = tbase + (((size_t)xi * GRES + yi) * GRES + zi) * 3;

        const float a0 = voxel_in[base + 0];
        const float a1 = voxel_in[base + 1];
        const float a2 = voxel_in[base + 2];

        vx += c[k] * a0;
        vy += c[k] * a1;
        vz += c[k] * a2;

        // update_lambda = sigmoid(lr * sigma_weight * coef)
        const float lam = 1.0f / (1.0f + expf(-lrsw * c[k]));

        atomicAdd(out_voxel + base + 0, lam * (tx - a0));
        atomicAdd(out_voxel + base + 1, lam * (ty - a1));
        atomicAdd(out_voxel + base + 2, lam * (tz - a2));
    }

    out_value[3 * i + 0] = vx;
    out_value[3 * i + 1] = vy;
    out_value[3 * i + 2] = vz;
}

extern "C" void kernel_launch(void* const* d_in, const int* in_sizes, int n_in,
                              void* d_out, int out_size, void* d_ws, size_t ws_size,
                              hipStream_t stream) {
    const int*   t      = (const int*)  d_in[0];
    const float* pos    = (const float*)d_in[1];
    const float* lr     = (const float*)d_in[2];
    const float* sigma  = (const float*)d_in[3];
    const float* target = (const float*)d_in[4];
    const float* voxel  = (const float*)d_in[5];

    const int N    = in_sizes[0];           // 1048576 points
    const int nvox = in_sizes[5];           // 8*128^3*3 floats

    float* out_value = (float*)d_out;
    float* out_voxel = out_value + (size_t)3 * N;

    // new_voxel starts as a copy of voxel_array; atomics then add diffs.
    hipMemcpyAsync(out_voxel, voxel, (size_t)nvox * sizeof(float),
                   hipMemcpyDeviceToDevice, stream);

    const int block = 256;
    const int grid  = (N + block - 1) / block;
    normvoxels_update<<<grid, block, 0, stream>>>(
        t, pos, lr, sigma, target, voxel, out_value, out_voxel, N);
}